// Round 1
// baseline (2077.632 us; speedup 1.0000x reference)
//
#include <hip/hip_runtime.h>
#include <hip/hip_bf16.h>
#include <stdint.h>

#define NN 50000
#define RR 5
#define AA 8
#define FF 128
#define TT 2
#define OO 128
#define KDIM 1024   // A*F
#define NCOLS 2048  // 8 rotations * T * O
#define RA 40       // R*A

typedef __attribute__((ext_vector_type(8))) short short8;
typedef __attribute__((ext_vector_type(4))) float f32x4;

__device__ inline void gload_lds16(const void* g, void* l) {
  __builtin_amdgcn_global_load_lds(
      (const __attribute__((address_space(1))) unsigned int*)g,
      (__attribute__((address_space(3))) unsigned int*)l, 16, 0, 0);
}

// ---------- prep: mesh->bf16, C2 = sum_r coeffs, BmatT (rotated weights, transposed) ----------
__global__ void prep_kernel(const float* __restrict__ mesh,
                            const float* __restrict__ coeffs,
                            const float* __restrict__ W,
                            __hip_bfloat16* __restrict__ meshb,
                            float* __restrict__ C2,
                            __hip_bfloat16* __restrict__ BmatT) {
  int tid = blockIdx.x * blockDim.x + threadIdx.x;
  int stride = gridDim.x * blockDim.x;
  for (int i = tid; i < NN * FF; i += stride)
    meshb[i] = __float2bfloat16(mesh[i]);
  for (int i = tid; i < AA * RA; i += stride) {
    int a = i / RA, k = i % RA;
    float s = 0.f;
    for (int r = 0; r < RR; ++r) s += coeffs[(r * AA + a) * RA + k];
    C2[i] = s;
  }
  // BmatT[c][kf], c = kr*256 + t*128 + o, kf = a*128 + f  ->  W[(a+kr)%8][t][o][f]
  for (int i = tid; i < NCOLS * KDIM; i += stride) {
    int c = i >> 10, kf = i & 1023;
    int kr = c >> 8, t = (c >> 7) & 1, o = c & 127;
    int a = kf >> 7, f = kf & 127;
    int arot = (a + kr) & 7;
    BmatT[i] = __float2bfloat16(W[((arot * TT + t) * OO + o) * FF + f]);
  }
}

// ---------- S: barycentric gather + C2 mixing ----------
__global__ __launch_bounds__(128) void s_kernel(
    const __hip_bfloat16* __restrict__ meshb,
    const float* __restrict__ bary_w,
    const int* __restrict__ bary_idx,
    const float* __restrict__ C2,
    __hip_bfloat16* __restrict__ Sout) {
  int n = blockIdx.x;
  int f = threadIdx.x;  // feature 0..127
  __shared__ float w_s[120];
  __shared__ int i_s[120];
  __shared__ float c2_s[AA * RA];
  if (f < 120) {
    w_s[f] = bary_w[n * 120 + f];
    i_s[f] = bary_idx[n * 120 + f];
  }
  for (int i = f; i < AA * RA; i += 128) c2_s[i] = C2[i];
  __syncthreads();
  float sig[RA];
#pragma unroll 8
  for (int k = 0; k < RA; ++k) {
    float acc = 0.f;
#pragma unroll
    for (int j = 0; j < 3; ++j)
      acc += w_s[k * 3 + j] * __bfloat162float(meshb[(long)i_s[k * 3 + j] * FF + f]);
    sig[k] = acc;
  }
#pragma unroll
  for (int a = 0; a < AA; ++a) {
    float s = 0.f;
#pragma unroll
    for (int k = 0; k < RA; ++k) s += c2_s[a * RA + k] * sig[k];
    Sout[(long)n * KDIM + a * FF + f] = __float2bfloat16(s);
  }
}

// ---------- GEMM (50000x1024)@(1024x2048 via BT) + bias/relu/sum_t epilogue ----------
// grid: (8 kr, 391 mtiles), block 512 = 8 waves (2 M x 4 N)
// tile: M=128, Ncols=256 (one kr block: t=0 cols 0..127, t=1 cols 128..255)
// wave computes 64 rows x {o in [wave_n*32, +32)} for BOTH t halves -> relu-sum is wave-local
__global__ __launch_bounds__(512) void gemm_kernel(
    const __hip_bfloat16* __restrict__ S,
    const __hip_bfloat16* __restrict__ BT,
    const float* __restrict__ bias,
    float* __restrict__ out) {
  int kr = blockIdx.x;
  int mt = blockIdx.y;
  int row0 = mt * 128;
  int col0 = kr * 256;
  int tid = threadIdx.x;
  int lane = tid & 63;
  int wid = tid >> 6;
  int wave_m = wid >> 2;   // 0..1
  int wave_n = wid & 3;    // 0..3

  // A-tile [128 rows][8 slots of 16B] at 0 (16KB); BT-tile [256 rows][8 slots] at 16KB (32KB)
  __shared__ __align__(16) char lds[49152];

  f32x4 acc[4][4];
#pragma unroll
  for (int m = 0; m < 4; ++m)
#pragma unroll
    for (int q = 0; q < 4; ++q) acc[m][q] = (f32x4){0.f, 0.f, 0.f, 0.f};

  for (int kt = 0; kt < KDIM / 64; ++kt) {
    int k0 = kt * 64;
    // stage A: rows row0..row0+127, 64 bf16 per row, swizzled source (rule #21)
#pragma unroll
    for (int i = 0; i < 2; ++i) {
      int li = i * 512 + tid;
      int r = li >> 3, s = li & 7;
      int sp = s ^ (r & 7);
      int row = row0 + r;
      if (row >= NN) row = NN - 1;
      gload_lds16(S + (long)row * KDIM + k0 + sp * 8, lds + li * 16);
    }
    // stage BT: rows col0..col0+255
#pragma unroll
    for (int i = 0; i < 4; ++i) {
      int li = i * 512 + tid;
      int r = li >> 3, s = li & 7;
      int sp = s ^ (r & 7);
      gload_lds16(BT + (long)(col0 + r) * KDIM + k0 + sp * 8, lds + 16384 + li * 16);
    }
    __syncthreads();
#pragma unroll
    for (int kk = 0; kk < 2; ++kk) {
      short8 afr[4], bfr[4];
#pragma unroll
      for (int m = 0; m < 4; ++m) {
        int arow = wave_m * 64 + m * 16 + (lane & 15);
        int slot = (kk * 4 + (lane >> 4)) ^ (arow & 7);
        afr[m] = *(const short8*)(lds + arow * 128 + slot * 16);
      }
#pragma unroll
      for (int q = 0; q < 4; ++q) {
        // q: 0,1 -> t=0 o-frags; 2,3 -> t=1 o-frags (same o range)
        int bcol = (q >> 1) * 128 + wave_n * 32 + (q & 1) * 16 + (lane & 15);
        int slot = (kk * 4 + (lane >> 4)) ^ (bcol & 7);
        bfr[q] = *(const short8*)(lds + 16384 + bcol * 128 + slot * 16);
      }
#pragma unroll
      for (int m = 0; m < 4; ++m)
#pragma unroll
        for (int q = 0; q < 4; ++q)
          acc[m][q] = __builtin_amdgcn_mfma_f32_16x16x32_bf16(afr[m], bfr[q], acc[m][q], 0, 0, 0);
    }
    __syncthreads();
  }

  // epilogue: out[n][kr][o] = relu(z_t0 + 40*b0) + relu(z_t1 + 40*b1)
  int olo = wave_n * 32 + (lane & 15);
  float b00 = 40.f * bias[olo];
  float b01 = 40.f * bias[olo + 16];
  float b10 = 40.f * bias[OO + olo];
  float b11 = 40.f * bias[OO + olo + 16];
#pragma unroll
  for (int m = 0; m < 4; ++m) {
#pragma unroll
    for (int i = 0; i < 4; ++i) {
      int node = row0 + wave_m * 64 + m * 16 + (lane >> 4) * 4 + i;
      if (node < NN) {
        float r0 = fmaxf(acc[m][0][i] + b00, 0.f) + fmaxf(acc[m][2][i] + b10, 0.f);
        float r1 = fmaxf(acc[m][1][i] + b01, 0.f) + fmaxf(acc[m][3][i] + b11, 0.f);
        long base = (long)node * 1024 + kr * 128;
        out[base + olo] = r0;
        out[base + olo + 16] = r1;
      }
    }
  }
}

extern "C" void kernel_launch(void* const* d_in, const int* in_sizes, int n_in,
                              void* d_out, int out_size, void* d_ws, size_t ws_size,
                              hipStream_t stream) {
  const float* mesh   = (const float*)d_in[0];
  const float* bary_w = (const float*)d_in[1];
  const float* W      = (const float*)d_in[2];
  const float* bias   = (const float*)d_in[3];
  const float* coeffs = (const float*)d_in[4];
  const int* bidx     = (const int*)d_in[5];
  float* out = (float*)d_out;
  char* ws = (char*)d_ws;

  __hip_bfloat16* meshb = (__hip_bfloat16*)ws;                    // 12,800,000 B
  float* C2             = (float*)(ws + 12800000);                // 1,280 B
  __hip_bfloat16* BmatT = (__hip_bfloat16*)(ws + 12801280);       // 4,194,304 B
  __hip_bfloat16* Smat  = (__hip_bfloat16*)(ws + 16995584);       // 102,400,000 B

  prep_kernel<<<dim3(2048), dim3(256), 0, stream>>>(mesh, coeffs, W, meshb, C2, BmatT);
  s_kernel<<<dim3(NN), dim3(128), 0, stream>>>(meshb, bary_w, bidx, C2, Smat);
  gemm_kernel<<<dim3(8, 391), dim3(512), 0, stream>>>(Smat, BmatT, bias, out);
}

// Round 3
// 449.582 us; speedup vs baseline: 4.6213x; 4.6213x over previous
//
#include <hip/hip_runtime.h>
#include <hip/hip_bf16.h>
#include <stdint.h>

#define NN 50000
#define RR 5
#define AA 8
#define FF 128
#define TT 2
#define OO 128
#define KDIM 1024   // A*F
#define NCOLS 2048  // 8 rotations * T * O
#define RA 40       // R*A

typedef __attribute__((ext_vector_type(8))) short short8;
typedef __attribute__((ext_vector_type(4))) float f32x4;
typedef __attribute__((ext_vector_type(4))) int i32x4;

__device__ inline void gload_lds16(const void* g, void* l) {
  __builtin_amdgcn_global_load_lds(
      (const __attribute__((address_space(1))) unsigned int*)g,
      (__attribute__((address_space(3))) unsigned int*)l, 16, 0, 0);
}

// ---------- prep: mesh->bf16 feature-sliced, C2 = sum_r coeffs, BmatT ----------
__global__ void prep_kernel(const float* __restrict__ mesh,
                            const float* __restrict__ coeffs,
                            const float* __restrict__ W,
                            __hip_bfloat16* __restrict__ meshq,  // [4][N][32]
                            float* __restrict__ C2,
                            __hip_bfloat16* __restrict__ BmatT) {
  int tid = blockIdx.x * blockDim.x + threadIdx.x;
  int stride = gridDim.x * blockDim.x;
  for (int i = tid; i < NN * FF; i += stride) {
    int n = i >> 7, f = i & 127;
    int p = f >> 5, fo = f & 31;
    meshq[((long)p * NN + n) * 32 + fo] = __float2bfloat16(mesh[i]);
  }
  for (int i = tid; i < AA * RA; i += stride) {
    int a = i / RA, k = i % RA;
    float s = 0.f;
    for (int r = 0; r < RR; ++r) s += coeffs[(r * AA + a) * RA + k];
    C2[i] = s;
  }
  // BmatT[c][kf], c = kr*256 + t*128 + o, kf = a*128 + f  ->  W[(a+kr)%8][t][o][f]
  for (int i = tid; i < NCOLS * KDIM; i += stride) {
    int c = i >> 10, kf = i & 1023;
    int kr = c >> 8, t = (c >> 7) & 1, o = c & 127;
    int a = kf >> 7, f = kf & 127;
    int arot = (a + kr) & 7;
    BmatT[i] = __float2bfloat16(W[((arot * TT + t) * OO + o) * FF + f]);
  }
}

// ---------- S pass p: gather 32-feature slice (L2-resident) + C2 mixing ----------
// block = 256 threads = 16 nodes x 16 lanes; lane covers 2 features (one uint).
__global__ __launch_bounds__(256) void s_pass_kernel(
    const __hip_bfloat16* __restrict__ meshq,
    const float* __restrict__ bary_w,
    const int* __restrict__ bary_idx,
    const float* __restrict__ C2,
    __hip_bfloat16* __restrict__ Sout,
    int p) {
  __shared__ float w_s[16 * 120];
  __shared__ int i_s[16 * 120];
  __shared__ float c2_s[AA * RA];
  int tid = threadIdx.x;
  long n0 = (long)blockIdx.x * 16;

  const f32x4* wsrc = (const f32x4*)(bary_w + n0 * 120);
  const i32x4* isrc = (const i32x4*)(bary_idx + n0 * 120);
  for (int i = tid; i < 480; i += 256) {
    f32x4 wv = __builtin_nontemporal_load(wsrc + i);
    ((f32x4*)w_s)[i] = wv;
    i32x4 iv = __builtin_nontemporal_load(isrc + i);
    ((i32x4*)i_s)[i] = iv;
  }
  for (int i = tid; i < AA * RA; i += 256) c2_s[i] = C2[i];
  __syncthreads();

  int g = tid >> 4;   // local node 0..15
  int fo = tid & 15;  // 4-byte slot within the 64B slice
  long n = n0 + g;
  const float* wg = w_s + g * 120;
  const int* ig = i_s + g * 120;
  const char* mbase = (const char*)(meshq + (long)p * NN * 32) + fo * 4;

  float sx_acc[AA], sy_acc[AA];
#pragma unroll
  for (int a = 0; a < AA; ++a) { sx_acc[a] = 0.f; sy_acc[a] = 0.f; }

#pragma unroll 2
  for (int k = 0; k < RA; ++k) {
    float sx = 0.f, sy = 0.f;
#pragma unroll
    for (int j = 0; j < 3; ++j) {
      int row = ig[k * 3 + j];
      unsigned u = *(const unsigned*)(mbase + (long)row * 64);
      float w = wg[k * 3 + j];
      sx += w * __uint_as_float(u << 16);
      sy += w * __uint_as_float(u & 0xffff0000u);
    }
#pragma unroll
    for (int a = 0; a < AA; ++a) {
      float c = c2_s[a * RA + k];
      sx_acc[a] += c * sx;
      sy_acc[a] += c * sy;
    }
  }

  long base = n * KDIM + p * 32 + fo * 2;
#pragma unroll
  for (int a = 0; a < AA; ++a) {
    __hip_bfloat16 hx = __float2bfloat16(sx_acc[a]);
    __hip_bfloat16 hy = __float2bfloat16(sy_acc[a]);
    unsigned u = (unsigned)*(unsigned short*)&hx | ((unsigned)*(unsigned short*)&hy << 16);
    __builtin_nontemporal_store(u, (unsigned*)(Sout + base + a * FF));
  }
}

// ---------- GEMM (50000x1024)@(1024x2048 via BT) + bias/relu/sum_t epilogue ----------
__global__ __launch_bounds__(512) void gemm_kernel(
    const __hip_bfloat16* __restrict__ S,
    const __hip_bfloat16* __restrict__ BT,
    const float* __restrict__ bias,
    float* __restrict__ out) {
  int kr = blockIdx.x;
  int mt = blockIdx.y;
  int row0 = mt * 128;
  int col0 = kr * 256;
  int tid = threadIdx.x;
  int lane = tid & 63;
  int wid = tid >> 6;
  int wave_m = wid >> 2;
  int wave_n = wid & 3;

  __shared__ __align__(16) char lds[49152];

  f32x4 acc[4][4];
#pragma unroll
  for (int m = 0; m < 4; ++m)
#pragma unroll
    for (int q = 0; q < 4; ++q) acc[m][q] = (f32x4){0.f, 0.f, 0.f, 0.f};

  for (int kt = 0; kt < KDIM / 64; ++kt) {
    int k0 = kt * 64;
#pragma unroll
    for (int i = 0; i < 2; ++i) {
      int li = i * 512 + tid;
      int r = li >> 3, s = li & 7;
      int sp = s ^ (r & 7);
      int row = row0 + r;
      if (row >= NN) row = NN - 1;
      gload_lds16(S + (long)row * KDIM + k0 + sp * 8, lds + li * 16);
    }
#pragma unroll
    for (int i = 0; i < 4; ++i) {
      int li = i * 512 + tid;
      int r = li >> 3, s = li & 7;
      int sp = s ^ (r & 7);
      gload_lds16(BT + (long)(col0 + r) * KDIM + k0 + sp * 8, lds + 16384 + li * 16);
    }
    __syncthreads();
#pragma unroll
    for (int kk = 0; kk < 2; ++kk) {
      short8 afr[4], bfr[4];
#pragma unroll
      for (int m = 0; m < 4; ++m) {
        int arow = wave_m * 64 + m * 16 + (lane & 15);
        int slot = (kk * 4 + (lane >> 4)) ^ (arow & 7);
        afr[m] = *(const short8*)(lds + arow * 128 + slot * 16);
      }
#pragma unroll
      for (int q = 0; q < 4; ++q) {
        int bcol = (q >> 1) * 128 + wave_n * 32 + (q & 1) * 16 + (lane & 15);
        int slot = (kk * 4 + (lane >> 4)) ^ (bcol & 7);
        bfr[q] = *(const short8*)(lds + 16384 + bcol * 128 + slot * 16);
      }
#pragma unroll
      for (int m = 0; m < 4; ++m)
#pragma unroll
        for (int q = 0; q < 4; ++q)
          acc[m][q] = __builtin_amdgcn_mfma_f32_16x16x32_bf16(afr[m], bfr[q], acc[m][q], 0, 0, 0);
    }
    __syncthreads();
  }

  int olo = wave_n * 32 + (lane & 15);
  float b00 = 40.f * bias[olo];
  float b01 = 40.f * bias[olo + 16];
  float b10 = 40.f * bias[OO + olo];
  float b11 = 40.f * bias[OO + olo + 16];
#pragma unroll
  for (int m = 0; m < 4; ++m) {
#pragma unroll
    for (int i = 0; i < 4; ++i) {
      int node = row0 + wave_m * 64 + m * 16 + (lane >> 4) * 4 + i;
      if (node < NN) {
        float r0 = fmaxf(acc[m][0][i] + b00, 0.f) + fmaxf(acc[m][2][i] + b10, 0.f);
        float r1 = fmaxf(acc[m][1][i] + b01, 0.f) + fmaxf(acc[m][3][i] + b11, 0.f);
        long base = (long)node * 1024 + kr * 128;
        out[base + olo] = r0;
        out[base + olo + 16] = r1;
      }
    }
  }
}

extern "C" void kernel_launch(void* const* d_in, const int* in_sizes, int n_in,
                              void* d_out, int out_size, void* d_ws, size_t ws_size,
                              hipStream_t stream) {
  const float* mesh   = (const float*)d_in[0];
  const float* bary_w = (const float*)d_in[1];
  const float* W      = (const float*)d_in[2];
  const float* bias   = (const float*)d_in[3];
  const float* coeffs = (const float*)d_in[4];
  const int* bidx     = (const int*)d_in[5];
  float* out = (float*)d_out;
  char* ws = (char*)d_ws;

  __hip_bfloat16* meshq = (__hip_bfloat16*)ws;                    // 12,800,000 B
  float* C2             = (float*)(ws + 12800000);                // 1,280 B
  __hip_bfloat16* BmatT = (__hip_bfloat16*)(ws + 12801280);       // 4,194,304 B
  __hip_bfloat16* Smat  = (__hip_bfloat16*)(ws + 16995584);       // 102,400,000 B

  prep_kernel<<<dim3(2048), dim3(256), 0, stream>>>(mesh, coeffs, W, meshq, C2, BmatT);
  for (int p = 0; p < 4; ++p)
    s_pass_kernel<<<dim3(3125), dim3(256), 0, stream>>>(meshq, bary_w, bidx, C2, Smat, p);
  gemm_kernel<<<dim3(8, 391), dim3(512), 0, stream>>>(Smat, BmatT, bias, out);
}

// Round 4
// 426.555 us; speedup vs baseline: 4.8707x; 1.0540x over previous
//
#include <hip/hip_runtime.h>
#include <hip/hip_bf16.h>
#include <stdint.h>

#define NN 50000
#define RR 5
#define AA 8
#define FF 128
#define TT 2
#define OO 128
#define KDIM 1024   // A*F
#define NCOLS 2048  // 8 rotations * T * O
#define RA 40       // R*A
#define NT 32       // KDIM / BK, BK=32

typedef __attribute__((ext_vector_type(8))) short short8;
typedef __attribute__((ext_vector_type(4))) float f32x4;
typedef __attribute__((ext_vector_type(4))) int i32x4;

__device__ inline void gload_lds16(const void* g, void* l) {
  __builtin_amdgcn_global_load_lds(
      (const __attribute__((address_space(1))) unsigned int*)g,
      (__attribute__((address_space(3))) unsigned int*)l, 16, 0, 0);
}

// ---------- prep: mesh->bf16 sliced, C2, BmatT, packed bary ----------
__global__ void prep_kernel(const float* __restrict__ mesh,
                            const float* __restrict__ coeffs,
                            const float* __restrict__ W,
                            const float* __restrict__ bary_w,
                            const int* __restrict__ bary_idx,
                            __hip_bfloat16* __restrict__ meshq,  // [4][N][32]
                            float* __restrict__ C2,
                            __hip_bfloat16* __restrict__ BmatT,
                            unsigned* __restrict__ packb,
                            int do_pack) {
  int tid = blockIdx.x * blockDim.x + threadIdx.x;
  int stride = gridDim.x * blockDim.x;
  for (int i = tid; i < NN * FF; i += stride) {
    int n = i >> 7, f = i & 127;
    int p = f >> 5, fo = f & 31;
    meshq[((long)p * NN + n) * 32 + fo] = __float2bfloat16(mesh[i]);
  }
  for (int i = tid; i < AA * RA; i += stride) {
    int a = i / RA, k = i % RA;
    float s = 0.f;
    for (int r = 0; r < RR; ++r) s += coeffs[(r * AA + a) * RA + k];
    C2[i] = s;
  }
  // BmatT[c][kf], c = kr*256 + t*128 + o, kf = a*128 + f  ->  W[(a+kr)%8][t][o][f]
  for (int i = tid; i < NCOLS * KDIM; i += stride) {
    int c = i >> 10, kf = i & 1023;
    int kr = c >> 8, t = (c >> 7) & 1, o = c & 127;
    int a = kf >> 7, f = kf & 127;
    int arot = (a + kr) & 7;
    BmatT[i] = __float2bfloat16(W[((arot * TT + t) * OO + o) * FF + f]);
  }
  if (do_pack) {
    for (int i = tid; i < NN * 120; i += stride) {
      __hip_bfloat16 h = __float2bfloat16(bary_w[i]);
      unsigned wb = *(unsigned short*)&h;
      packb[i] = ((unsigned)bary_idx[i] << 16) | wb;
    }
  }
}

// ---------- S pass (packed): gather 32-feature slice + C2 mixing ----------
__global__ __launch_bounds__(256) void s_pass_packed(
    const __hip_bfloat16* __restrict__ meshq,
    const unsigned* __restrict__ packb,
    const float* __restrict__ C2,
    __hip_bfloat16* __restrict__ Sout,
    int p) {
  __shared__ unsigned pk_s[16 * 120];
  __shared__ float c2_s[AA * RA];
  int tid = threadIdx.x;
  long n0 = (long)blockIdx.x * 16;
  const i32x4* psrc = (const i32x4*)(packb + n0 * 120);
  for (int i = tid; i < 480; i += 256) {
    i32x4 v = __builtin_nontemporal_load(psrc + i);
    ((i32x4*)pk_s)[i] = v;
  }
  for (int i = tid; i < AA * RA; i += 256) c2_s[i] = C2[i];
  __syncthreads();

  int g = tid >> 4;
  int fo = tid & 15;
  long n = n0 + g;
  const unsigned* pg = pk_s + g * 120;
  const char* mbase = (const char*)(meshq + (long)p * NN * 32) + fo * 4;

  float sx_acc[AA], sy_acc[AA];
#pragma unroll
  for (int a = 0; a < AA; ++a) { sx_acc[a] = 0.f; sy_acc[a] = 0.f; }

#pragma unroll 2
  for (int k = 0; k < RA; ++k) {
    float sx = 0.f, sy = 0.f;
#pragma unroll
    for (int j = 0; j < 3; ++j) {
      unsigned v = pg[k * 3 + j];
      unsigned row = v >> 16;
      float w = __uint_as_float(v << 16);
      unsigned u = *(const unsigned*)(mbase + (long)row * 64);
      sx += w * __uint_as_float(u << 16);
      sy += w * __uint_as_float(u & 0xffff0000u);
    }
#pragma unroll
    for (int a = 0; a < AA; ++a) {
      float c = c2_s[a * RA + k];
      sx_acc[a] += c * sx;
      sy_acc[a] += c * sy;
    }
  }

  long base = n * KDIM + p * 32 + fo * 2;
#pragma unroll
  for (int a = 0; a < AA; ++a) {
    __hip_bfloat16 hx = __float2bfloat16(sx_acc[a]);
    __hip_bfloat16 hy = __float2bfloat16(sy_acc[a]);
    unsigned u = (unsigned)*(unsigned short*)&hx | ((unsigned)*(unsigned short*)&hy << 16);
    __builtin_nontemporal_store(u, (unsigned*)(Sout + base + a * FF));
  }
}

// ---------- S pass (legacy fallback, identical to R3 version) ----------
__global__ __launch_bounds__(256) void s_pass_kernel(
    const __hip_bfloat16* __restrict__ meshq,
    const float* __restrict__ bary_w,
    const int* __restrict__ bary_idx,
    const float* __restrict__ C2,
    __hip_bfloat16* __restrict__ Sout,
    int p) {
  __shared__ float w_s[16 * 120];
  __shared__ int i_s[16 * 120];
  __shared__ float c2_s[AA * RA];
  int tid = threadIdx.x;
  long n0 = (long)blockIdx.x * 16;
  const f32x4* wsrc = (const f32x4*)(bary_w + n0 * 120);
  const i32x4* isrc = (const i32x4*)(bary_idx + n0 * 120);
  for (int i = tid; i < 480; i += 256) {
    f32x4 wv = __builtin_nontemporal_load(wsrc + i);
    ((f32x4*)w_s)[i] = wv;
    i32x4 iv = __builtin_nontemporal_load(isrc + i);
    ((i32x4*)i_s)[i] = iv;
  }
  for (int i = tid; i < AA * RA; i += 256) c2_s[i] = C2[i];
  __syncthreads();
  int g = tid >> 4;
  int fo = tid & 15;
  long n = n0 + g;
  const float* wg = w_s + g * 120;
  const int* ig = i_s + g * 120;
  const char* mbase = (const char*)(meshq + (long)p * NN * 32) + fo * 4;
  float sx_acc[AA], sy_acc[AA];
#pragma unroll
  for (int a = 0; a < AA; ++a) { sx_acc[a] = 0.f; sy_acc[a] = 0.f; }
#pragma unroll 2
  for (int k = 0; k < RA; ++k) {
    float sx = 0.f, sy = 0.f;
#pragma unroll
    for (int j = 0; j < 3; ++j) {
      int row = ig[k * 3 + j];
      unsigned u = *(const unsigned*)(mbase + (long)row * 64);
      float w = wg[k * 3 + j];
      sx += w * __uint_as_float(u << 16);
      sy += w * __uint_as_float(u & 0xffff0000u);
    }
#pragma unroll
    for (int a = 0; a < AA; ++a) {
      float c = c2_s[a * RA + k];
      sx_acc[a] += c * sx;
      sy_acc[a] += c * sy;
    }
  }
  long base = n * KDIM + p * 32 + fo * 2;
#pragma unroll
  for (int a = 0; a < AA; ++a) {
    __hip_bfloat16 hx = __float2bfloat16(sx_acc[a]);
    __hip_bfloat16 hy = __float2bfloat16(sy_acc[a]);
    unsigned u = (unsigned)*(unsigned short*)&hx | ((unsigned)*(unsigned short*)&hy << 16);
    __builtin_nontemporal_store(u, (unsigned*)(Sout + base + a * FF));
  }
}

// ---------- GEMM: 256x256 tile, BK=32, triple-buffer LDS, counted vmcnt ----------
// grid (8, 200): bx = XCD slot, by -> (kr = by&7, mt = (by>>3)*8 + bx)
// 512 threads = 8 waves (2M x 4N); per-wave 128 rows x 32 o-cols x both t halves.
__global__ __launch_bounds__(512, 1) void gemm_kernel(
    const __hip_bfloat16* __restrict__ S,
    const __hip_bfloat16* __restrict__ BT,
    const float* __restrict__ bias,
    float* __restrict__ out) {
  int bx = blockIdx.x;
  int by = blockIdx.y;
  int kr = by & 7;
  int mt = ((by >> 3) << 3) + bx;
  if (mt >= 196) return;
  int row0 = mt * 256;
  int col0 = kr * 256;

  int tid = threadIdx.x;
  int lane = tid & 63;
  int wid = tid >> 6;
  int wave_m = wid >> 2;   // 0..1
  int wave_n = wid & 3;    // 0..3

  // 3 buffers x (A 16KB + B 16KB). Row = 64B = 4 slots of 16B, slot ^= (r>>1)&3.
  __shared__ __align__(16) char lds[98304];

  f32x4 acc[8][4];
#pragma unroll
  for (int m = 0; m < 8; ++m)
#pragma unroll
    for (int q = 0; q < 4; ++q) acc[m][q] = (f32x4){0.f, 0.f, 0.f, 0.f};

#define STAGE(T, B)                                                         \
  {                                                                         \
    int k0_ = (T) * 32;                                                     \
    char* base_ = lds + (B) * 32768;                                        \
    _Pragma("unroll")                                                       \
    for (int i_ = 0; i_ < 2; ++i_) {                                        \
      int li_ = i_ * 512 + tid;                                             \
      int r_ = li_ >> 2, sp_ = li_ & 3;                                     \
      int sl_ = sp_ ^ ((r_ >> 1) & 3);                                      \
      int row_ = row0 + r_;                                                 \
      if (row_ >= NN) row_ = NN - 1;                                        \
      gload_lds16(S + (long)row_ * KDIM + k0_ + sl_ * 8, base_ + li_ * 16); \
    }                                                                       \
    _Pragma("unroll")                                                       \
    for (int i_ = 0; i_ < 2; ++i_) {                                        \
      int li_ = i_ * 512 + tid;                                             \
      int r_ = li_ >> 2, sp_ = li_ & 3;                                     \
      int sl_ = sp_ ^ ((r_ >> 1) & 3);                                      \
      gload_lds16(BT + (long)(col0 + r_) * KDIM + k0_ + sl_ * 8,            \
                  base_ + 16384 + li_ * 16);                                \
    }                                                                       \
  }

  STAGE(0, 0)
  STAGE(1, 1)

  int bcur = 0, bstage = 2;
  for (int t = 0; t < NT; ++t) {
    if (t < NT - 1) {
      asm volatile("s_waitcnt vmcnt(4)" ::: "memory");
    } else {
      asm volatile("s_waitcnt vmcnt(0)" ::: "memory");
    }
    __builtin_amdgcn_sched_barrier(0);
    __builtin_amdgcn_s_barrier();
    __builtin_amdgcn_sched_barrier(0);
    if (t + 2 < NT) STAGE(t + 2, bstage)
    const char* base = lds + bcur * 32768;
    short8 afr[8], bfr[4];
#pragma unroll
    for (int m = 0; m < 8; ++m) {
      int r = wave_m * 128 + m * 16 + (lane & 15);
      int phys = (lane >> 4) ^ ((r >> 1) & 3);
      afr[m] = *(const short8*)(base + r * 64 + phys * 16);
    }
#pragma unroll
    for (int q = 0; q < 4; ++q) {
      int c = (q >> 1) * 128 + wave_n * 32 + (q & 1) * 16 + (lane & 15);
      int phys = (lane >> 4) ^ ((c >> 1) & 3);
      bfr[q] = *(const short8*)(base + 16384 + c * 64 + phys * 16);
    }
    __builtin_amdgcn_s_setprio(1);
#pragma unroll
    for (int m = 0; m < 8; ++m)
#pragma unroll
      for (int q = 0; q < 4; ++q)
        acc[m][q] = __builtin_amdgcn_mfma_f32_16x16x32_bf16(afr[m], bfr[q], acc[m][q], 0, 0, 0);
    __builtin_amdgcn_s_setprio(0);
    __builtin_amdgcn_sched_barrier(0);
    bcur = (bcur == 2) ? 0 : bcur + 1;
    bstage = (bstage == 2) ? 0 : bstage + 1;
  }

  // epilogue: out[n][kr][o] = relu(z_t0 + 40*b0) + relu(z_t1 + 40*b1)
  int olo = wave_n * 32 + (lane & 15);
  float b00 = 40.f * bias[olo];
  float b01 = 40.f * bias[olo + 16];
  float b10 = 40.f * bias[OO + olo];
  float b11 = 40.f * bias[OO + olo + 16];
#pragma unroll
  for (int m = 0; m < 8; ++m) {
#pragma unroll
    for (int i = 0; i < 4; ++i) {
      int node = row0 + wave_m * 128 + m * 16 + (lane >> 4) * 4 + i;
      if (node < NN) {
        float r0 = fmaxf(acc[m][0][i] + b00, 0.f) + fmaxf(acc[m][2][i] + b10, 0.f);
        float r1 = fmaxf(acc[m][1][i] + b01, 0.f) + fmaxf(acc[m][3][i] + b11, 0.f);
        long base = (long)node * 1024 + kr * 128;
        __builtin_nontemporal_store(r0, out + base + olo);
        __builtin_nontemporal_store(r1, out + base + olo + 16);
      }
    }
  }
}

extern "C" void kernel_launch(void* const* d_in, const int* in_sizes, int n_in,
                              void* d_out, int out_size, void* d_ws, size_t ws_size,
                              hipStream_t stream) {
  const float* mesh   = (const float*)d_in[0];
  const float* bary_w = (const float*)d_in[1];
  const float* W      = (const float*)d_in[2];
  const float* bias   = (const float*)d_in[3];
  const float* coeffs = (const float*)d_in[4];
  const int* bidx     = (const int*)d_in[5];
  float* out = (float*)d_out;
  char* ws = (char*)d_ws;

  __hip_bfloat16* meshq = (__hip_bfloat16*)ws;                    // 12,800,000 B
  float* C2             = (float*)(ws + 12800000);                // 1,280 B
  __hip_bfloat16* BmatT = (__hip_bfloat16*)(ws + 12801280);       // 4,194,304 B
  __hip_bfloat16* Smat  = (__hip_bfloat16*)(ws + 16995584);       // 102,400,000 B
  unsigned* packb       = (unsigned*)(ws + 119395584);            // 24,000,000 B

  int do_pack = (ws_size >= 143395584UL) ? 1 : 0;

  prep_kernel<<<dim3(2048), dim3(256), 0, stream>>>(mesh, coeffs, W, bary_w, bidx,
                                                    meshq, C2, BmatT, packb, do_pack);
  if (do_pack) {
    for (int p = 0; p < 4; ++p)
      s_pass_packed<<<dim3(3125), dim3(256), 0, stream>>>(meshq, packb, C2, Smat, p);
  } else {
    for (int p = 0; p < 4; ++p)
      s_pass_kernel<<<dim3(3125), dim3(256), 0, stream>>>(meshq, bary_w, bidx, C2, Smat, p);
  }
  gemm_kernel<<<dim3(8, 200), dim3(512), 0, stream>>>(Smat, BmatT, bias, out);
}